// Round 1
// baseline (45.405 us; speedup 1.0000x reference)
//
#include <hip/hip_runtime.h>
#include <math.h>

#define NQ     12
#define DIM    4096          // 2^12
#define DEPTH  6
#define NBATCH 256
#define NTHREADS 256

// One block per batch element. Real-valued state vector simulation.
// state[j] lives in LDS; 12 butterfly gates per depth + Gray-code permutation.
__global__ __launch_bounds__(NTHREADS)
void qnet_kernel(const float* __restrict__ x,      // [NBATCH, NQ]
                 const float* __restrict__ thetas, // [DEPTH, NQ]
                 float* __restrict__ out)          // [NBATCH, 3]
{
    __shared__ float st[DIM];
    __shared__ float gc[DEPTH * NQ];
    __shared__ float gs[DEPTH * NQ];
    __shared__ float ec[NQ];
    __shared__ float es[NQ];
    __shared__ float red[4 * 3];   // 4 waves x 3 observables

    const int b   = blockIdx.x;
    const int tid = threadIdx.x;

    // ---- trig tables ----
    if (tid < DEPTH * NQ) {
        float h = thetas[tid] * 0.5f;
        gc[tid] = cosf(h);
        gs[tid] = sinf(h);
    }
    if (tid < NQ) {
        // encoder half-angle: x * pi/2
        float h = x[b * NQ + tid] * 1.57079632679489662f;
        ec[tid] = cosf(h);
        es[tid] = sinf(h);
    }
    __syncthreads();

    // ---- encoder: product state ----
    // state[j] = prod_q ( bit_{11-q}(j) ? sin : cos )
    #pragma unroll
    for (int r = 0; r < DIM / NTHREADS; ++r) {
        int j = tid + NTHREADS * r;
        float v = 1.0f;
        #pragma unroll
        for (int q = 0; q < NQ; ++q) {
            int bit = (j >> (NQ - 1 - q)) & 1;
            v *= bit ? es[q] : ec[q];
        }
        st[j] = v;
    }
    __syncthreads();

    // ---- ansatz ----
    for (int d = 0; d < DEPTH; ++d) {
        // 12 single-qubit RY butterflies (they commute; order by bit position)
        for (int bq = 0; bq < NQ; ++bq) {
            int q = NQ - 1 - bq;              // gate on qubit q acts on bit bq
            float c = gc[d * NQ + q];
            float s = gs[d * NQ + q];
            #pragma unroll
            for (int r = 0; r < (DIM / 2) / NTHREADS; ++r) {
                int p  = tid + NTHREADS * r;                  // pair index
                int lo = p & ((1 << bq) - 1);
                int i0 = ((p >> bq) << (bq + 1)) | lo;
                int i1 = i0 | (1 << bq);
                float a0 = st[i0];
                float a1 = st[i1];
                st[i0] = c * a0 - s * a1;
                st[i1] = s * a0 + c * a1;
            }
            __syncthreads();
        }
        // CNOT ladder == Gray-code permutation: new[j] = old[j ^ (j>>1)]
        float tmp[DIM / NTHREADS];
        #pragma unroll
        for (int r = 0; r < DIM / NTHREADS; ++r) {
            int j = tid + NTHREADS * r;
            tmp[r] = st[j ^ (j >> 1)];
        }
        __syncthreads();
        #pragma unroll
        for (int r = 0; r < DIM / NTHREADS; ++r) {
            st[tid + NTHREADS * r] = tmp[r];
        }
        __syncthreads();
    }

    // ---- observer: <Z_q> for q = 0,1,2 -> bits 11,10,9 ----
    float acc0 = 0.f, acc1 = 0.f, acc2 = 0.f;
    #pragma unroll
    for (int r = 0; r < DIM / NTHREADS; ++r) {
        int j = tid + NTHREADS * r;
        float v = st[j];
        float p = v * v;
        acc0 += ((j >> 11) & 1) ? -p : p;
        acc1 += ((j >> 10) & 1) ? -p : p;
        acc2 += ((j >> 9)  & 1) ? -p : p;
    }
    // wave (64-lane) reduction
    #pragma unroll
    for (int off = 32; off > 0; off >>= 1) {
        acc0 += __shfl_down(acc0, off);
        acc1 += __shfl_down(acc1, off);
        acc2 += __shfl_down(acc2, off);
    }
    int lane = tid & 63;
    int w    = tid >> 6;
    if (lane == 0) {
        red[w * 3 + 0] = acc0;
        red[w * 3 + 1] = acc1;
        red[w * 3 + 2] = acc2;
    }
    __syncthreads();
    if (tid == 0) {
        float o0 = red[0] + red[3] + red[6] + red[9];
        float o1 = red[1] + red[4] + red[7] + red[10];
        float o2 = red[2] + red[5] + red[8] + red[11];
        out[b * 3 + 0] = o0;
        out[b * 3 + 1] = o1;
        out[b * 3 + 2] = o2;
    }
}

extern "C" void kernel_launch(void* const* d_in, const int* in_sizes, int n_in,
                              void* d_out, int out_size, void* d_ws, size_t ws_size,
                              hipStream_t stream) {
    (void)in_sizes; (void)n_in; (void)out_size; (void)d_ws; (void)ws_size;
    const float* x      = (const float*)d_in[0];   // [256,12] f32
    const float* thetas = (const float*)d_in[1];   // [6,12]   f32
    float* out          = (float*)d_out;           // [256,3]  f32

    qnet_kernel<<<dim3(NBATCH), dim3(NTHREADS), 0, stream>>>(x, thetas, out);
}